// Round 13
// baseline (286.805 us; speedup 1.0000x reference)
//
#include <hip/hip_runtime.h>

#define NBLK 256
#define GBLK 128            // active GEMM blocks (BN=32)
#define NTHR 1024
#define BSZ 64
#define DIM 4096
#define MEM 5
#define MAXIT 50
#define TOL_ 0.01f
#define LAM_ 1e-4f

// float-region workspace layout (float offsets)
#define X_OFF 0
#define F_OFF (BSZ * MEM * DIM)
#define Z_OFF (2 * BSZ * MEM * DIM)
#define RP_OFF (Z_OFF + BSZ * DIM)              // residual partials [2][256]
#define BAR_OFF (RP_OFF + 640)                  // flags[256] + go (memset 0 per launch)
#define FP32_WS_FLOATS (RP_OFF + 1024)
// fp16 regions appended (byte offsets)
#define ZF_BYTE ((size_t)(RP_OFF + 1024) * 4)
#define WF_BYTE (ZF_BYTE + (size_t)BSZ * DIM * 2)
#define WS_NEED (WF_BYTE + (size_t)DIM * DIM * 2)

typedef __attribute__((ext_vector_type(8))) _Float16 half8v;  // 8 fp16 (4 VGPRs)
typedef __attribute__((ext_vector_type(4))) float f32x4;

__device__ __forceinline__ unsigned short f2h(float f) {
    _Float16 h = (_Float16)f;           // RNE
    unsigned short u;
    __builtin_memcpy(&u, &h, 2);
    return u;
}

// ---- two-leg grid barrier (r9-exact, empirically best of 4 variants) ----
__device__ __forceinline__ void gridbar(unsigned int* flags, unsigned int* go,
                                        unsigned int e)
{
    __syncthreads();
    const int tid = threadIdx.x;
    if (blockIdx.x == 0) {
        if (tid == 0) {
            __builtin_amdgcn_fence(__ATOMIC_RELEASE, "agent");
            __hip_atomic_store(&flags[0], e, __ATOMIC_RELAXED,
                               __HIP_MEMORY_SCOPE_AGENT);
        }
        if (tid < NBLK) {
            while (__hip_atomic_load(&flags[tid], __ATOMIC_RELAXED,
                                     __HIP_MEMORY_SCOPE_AGENT) < e)
                __builtin_amdgcn_s_sleep(1);
        }
        __syncthreads();
        if (tid == 0) {
            __builtin_amdgcn_fence(__ATOMIC_ACQUIRE, "agent");
            __hip_atomic_store(go, e, __ATOMIC_RELAXED,
                               __HIP_MEMORY_SCOPE_AGENT);
        }
    } else {
        if (tid == 0) {
            __builtin_amdgcn_fence(__ATOMIC_RELEASE, "agent");
            __hip_atomic_store(&flags[blockIdx.x], e, __ATOMIC_RELAXED,
                               __HIP_MEMORY_SCOPE_AGENT);
            while (__hip_atomic_load(go, __ATOMIC_RELAXED,
                                     __HIP_MEMORY_SCOPE_AGENT) < e)
                __builtin_amdgcn_s_sleep(1);
            __builtin_amdgcn_fence(__ATOMIC_ACQUIRE, "agent");
        }
    }
    __syncthreads();
}

// ---------------- one-time W -> packed fp16 conversion ----------------
// Layout per 16-col group ng: Wf[ng*65536 + ks*512 + lane*8 + e],
// k = ks*32 + (lane>>4)*8 + e, j = ng*16 + (lane&15).
__device__ void convert_w(const float* __restrict__ W, unsigned short* __restrict__ Wf,
                          float* smem)
{
    const int tid = threadIdx.x;
    const int blk = blockIdx.x;
    const int jc = blk << 4;
    for (int sc = 0; sc < 8; ++sc) {
        __syncthreads();
        #pragma unroll
        for (int h = 0; h < 2; ++h) {
            int rrow = (tid >> 2) + (h << 8);
            int seg = tid & 3;
            float4 v = *(const float4*)&W[(size_t)((sc << 9) + rrow) * DIM + jc + (seg << 2)];
            float* dst = smem + rrow * 17 + (seg << 2);
            dst[0] = v.x; dst[1] = v.y; dst[2] = v.z; dst[3] = v.w;
        }
        __syncthreads();
        unsigned int* of = (unsigned int*)(Wf + ((size_t)blk * 128 + sc * 16) * 512);
        #pragma unroll
        for (int it = 0; it < 4; ++it) {
            int o = tid + (it << 10);
            int ksl = o >> 8, ln = (o >> 2) & 63, ep = o & 3;
            int kl = (ksl << 5) + ((ln >> 4) << 3) + (ep << 1);
            float w0 = smem[kl * 17 + (ln & 15)];
            float w1 = smem[(kl + 1) * 17 + (ln & 15)];
            of[o] = (unsigned int)f2h(w0) | ((unsigned int)f2h(w1) << 16);
        }
    }
    __syncthreads();
}

// ------- fp16 MFMA GEMM + tanh + residual partials (BN=32) -------
// PRE=true (loop only): prefetch first B fragments BEFORE the barrier spin.
// Safe ONLY when Wf is immutable AND already release-published in an earlier
// epoch (r12 lesson: in the init epoch other blocks' Wf writes are not yet
// visible -> reads poison; use PRE=false there).
template <bool PRE>
__device__ __forceinline__ void gemm_tanh_mfma(
    int idx, const float* __restrict__ x, const float* __restrict__ bias,
    const unsigned short* __restrict__ Zf, const unsigned short* __restrict__ Wf,
    float* __restrict__ Z, float* __restrict__ Fs, float* __restrict__ rp, float* smem,
    unsigned int* flags, unsigned int* go, unsigned int ep)
{
    const int tid = threadIdx.x;
    const int cb = blockIdx.x;              // 0..127
    const int lane = tid & 63;
    const int w = tid >> 6;                 // wave 0..15
    const int r0 = lane & 15;
    const int kg = lane >> 4;
    f32x4 acc[4][2] = {};

    const unsigned short* b0 = Wf + (size_t)(cb * 2) * 65536;
    const unsigned short* b1 = Wf + (size_t)(cb * 2 + 1) * 65536;
    const int ksbase = w << 3;
    const size_t bo0 = ((size_t)ksbase << 9) + (lane << 3);

    half8v B0p, B1p;
    if constexpr (PRE) {
        // pre-barrier W prefetch (immutable, published in earlier epoch)
        B0p = *(const half8v*)(b0 + bo0);
        B1p = *(const half8v*)(b1 + bo0);
        gridbar(flags, go, ep);
    } else {
        gridbar(flags, go, ep);
        B0p = *(const half8v*)(b0 + bo0);
        B1p = *(const half8v*)(b1 + bo0);
    }

    // s = 0 with (pre)fetched B
    {
        const int kbase = (ksbase << 5) + (kg << 3);
        #pragma unroll
        for (int m = 0; m < 4; ++m) {
            const size_t ao = (size_t)((m << 4) + r0) * DIM + kbase;
            half8v Ah = *(const half8v*)(Zf + ao);
            acc[m][0] = __builtin_amdgcn_mfma_f32_16x16x32_f16(Ah, B0p, acc[m][0], 0, 0, 0);
            acc[m][1] = __builtin_amdgcn_mfma_f32_16x16x32_f16(Ah, B1p, acc[m][1], 0, 0, 0);
        }
    }
    #pragma unroll 2
    for (int s = 1; s < 8; ++s) {
        const int ks = ksbase + s;
        const size_t bo = ((size_t)ks << 9) + (lane << 3);
        half8v B0 = *(const half8v*)(b0 + bo);
        half8v B1 = *(const half8v*)(b1 + bo);
        const int kbase = (ks << 5) + (kg << 3);
        #pragma unroll
        for (int m = 0; m < 4; ++m) {
            const size_t ao = (size_t)((m << 4) + r0) * DIM + kbase;
            half8v Ah = *(const half8v*)(Zf + ao);
            acc[m][0] = __builtin_amdgcn_mfma_f32_16x16x32_f16(Ah, B0, acc[m][0], 0, 0, 0);
            acc[m][1] = __builtin_amdgcn_mfma_f32_16x16x32_f16(Ah, B1, acc[m][1], 0, 0, 0);
        }
    }
    // cross-wave reduce: 4 rounds of 4 sections; section = 2048 floats + pad 4
    const int row = tid >> 4, cc = tid & 15;
    const int m_o = row >> 4, rl = row & 15;
    const int lsrc = cc + ((rl >> 2) << 4), reg = rl & 3;
    float sum0 = 0.f, sum1 = 0.f;
    #pragma unroll
    for (int rnd = 0; rnd < 4; ++rnd) {
        __syncthreads();
        if ((w >> 2) == rnd) {
            float* sec = smem + (w & 3) * 2052;
            #pragma unroll
            for (int m = 0; m < 4; ++m) {
                *(f32x4*)(sec + ((m * 2 + 0) << 8) + (lane << 2)) = acc[m][0];
                *(f32x4*)(sec + ((m * 2 + 1) << 8) + (lane << 2)) = acc[m][1];
            }
        }
        __syncthreads();
        #pragma unroll
        for (int p = 0; p < 4; ++p) {
            sum0 += smem[p * 2052 + ((m_o * 2 + 0) << 8) + (lsrc << 2) + reg];
            sum1 += smem[p * 2052 + ((m_o * 2 + 1) << 8) + (lsrc << 2) + reg];
        }
    }
    // epilogue: tanh, F-slot write, residual partials (2 cols/thread)
    const int j0 = (cb << 5) + cc;
    const int j1 = j0 + 16;
    float fz0 = tanhf(sum0 + x[(row << 12) + j0] + bias[j0]);
    float fz1 = tanhf(sum1 + x[(row << 12) + j1] + bias[j1]);
    Fs[(row * MEM + idx) * DIM + j0] = fz0;
    Fs[(row * MEM + idx) * DIM + j1] = fz1;
    float d0 = fz0 - Z[(row << 12) + j0];
    float d1 = fz1 - Z[(row << 12) + j1];
    float lnum = d0 * d0 + d1 * d1;
    float lden = fz0 * fz0 + fz1 * fz1;
    #pragma unroll
    for (int off = 1; off < 64; off <<= 1) {
        lnum += __shfl_xor(lnum, off, 64);
        lden += __shfl_xor(lden, off, 64);
    }
    if (lane == 0) { smem[8448 + w] = lnum; smem[8480 + w] = lden; }
    __syncthreads();
    if (tid == 0) {
        float a = 0.f, b2 = 0.f;
        #pragma unroll
        for (int i = 0; i < 16; ++i) { a += smem[8448 + i]; b2 += smem[8480 + i]; }
        rp[cb] = a;
        rp[NBLK + cb] = b2;
    }
}

// ---------------- fp32 fallback GEMM (round-2, proven; 256 blocks) ----------
__device__ __forceinline__ void gemm_tanh_fp32(
    int idx, const float* __restrict__ x, const float* __restrict__ W,
    const float* __restrict__ bias, float* __restrict__ wsf, float* smem)
{
    const int tid = threadIdx.x;
    const int blk = blockIdx.x;
    const int lane = tid & 63;
    const int w = tid >> 6;
    const int r = w >> 2;
    const int q = w & 3;
    const int jcq = (blk << 4) + (q << 2);
    float* Z = wsf + Z_OFF;
    float* Fs = wsf + F_OFF;
    float* rp = wsf + RP_OFF;

    float acc0 = 0.f, acc1 = 0.f, acc2 = 0.f, acc3 = 0.f;
    const int lx = lane & 15;
    const float* inrow = smem + (r << 12) + (lane << 6);
    const int srow = tid >> 4;
    const int sg = tid & 15;

    for (int step = 0; step < 16; ++step) {
        #pragma unroll
        for (int i = 0; i < 4; ++i) {
            float4 v = *(const float4*)&Z[srow * DIM + (i << 10) + (step << 6) + (sg << 2)];
            *(float4*)&smem[(i << 12) + (srow << 6) + ((sg ^ (srow & 15)) << 2)] = v;
        }
        __syncthreads();
        const float* wbase = W + (size_t)((r << 10) + (step << 6)) * DIM + jcq;
        #pragma unroll 2
        for (int s = 0; s < 16; ++s) {
            float4 in4 = *(const float4*)&inrow[(s ^ lx) << 2];
            const float* wr = wbase + (size_t)(s << 2) * DIM;
            #pragma unroll
            for (int t = 0; t < 4; ++t) {
                float iv = (t == 0) ? in4.x : (t == 1) ? in4.y : (t == 2) ? in4.z : in4.w;
                float4 wq = *(const float4*)(wr + (size_t)t * DIM);
                acc0 = fmaf(iv, wq.x, acc0);
                acc1 = fmaf(iv, wq.y, acc1);
                acc2 = fmaf(iv, wq.z, acc2);
                acc3 = fmaf(iv, wq.w, acc3);
            }
        }
        __syncthreads();
    }
    {
        float* rrow = smem + r * 1088 + lane * 17 + (q << 2);
        rrow[0] = acc0; rrow[1] = acc1; rrow[2] = acc2; rrow[3] = acc3;
    }
    __syncthreads();
    const int row = tid >> 4, cc = tid & 15;
    const int boff = row * 17 + cc;
    float sum = smem[boff] + smem[1088 + boff] + smem[2176 + boff] + smem[3264 + boff];
    const int j = (blk << 4) + cc;
    float fz = tanhf(sum + x[(row << 12) + j] + bias[j]);
    Fs[(row * MEM + idx) * DIM + j] = fz;
    float d = fz - Z[(row << 12) + j];
    float lnum = d * d, lden = fz * fz;
    #pragma unroll
    for (int off = 1; off < 64; off <<= 1) {
        lnum += __shfl_xor(lnum, off, 64);
        lden += __shfl_xor(lden, off, 64);
    }
    if (lane == 0) { smem[8448 + w] = lnum; smem[8480 + w] = lden; }
    __syncthreads();
    if (tid == 0) {
        float a = 0.f, b2 = 0.f;
        for (int i = 0; i < 16; ++i) { a += smem[8448 + i]; b2 += smem[8480 + i]; }
        rp[blk] = a;
        rp[NBLK + blk] = b2;
    }
}

// ---------------- residual reduce (every block, deterministic) -----------
__device__ __forceinline__ float phase_res(const float* __restrict__ rp, float* smem)
{
    const int tid = threadIdx.x;
    const int lane = tid & 63, w = tid >> 6;
    float a = (tid < NBLK) ? rp[tid] : 0.f;
    float b = (tid < NBLK) ? rp[NBLK + tid] : 0.f;
    #pragma unroll
    for (int off = 1; off < 64; off <<= 1) {
        a += __shfl_xor(a, off, 64);
        b += __shfl_xor(b, off, 64);
    }
    if (lane == 0) { smem[w] = a; smem[16 + w] = b; }
    __syncthreads();
    if (tid == 0) {
        float sa = 0.f, sb = 0.f;
        for (int i = 0; i < 16; ++i) { sa += smem[i]; sb += smem[16 + i]; }
        smem[32] = sqrtf(sa) / (1e-5f + sqrtf(sb));
    }
    __syncthreads();
    float res = smem[32];
    __syncthreads();
    return res;
}

// ---- per-batch-row: Gram + 6x6 bordered solve + alpha-combine ----
// F fragments register-cached across the solve (reused by combine).
template <bool F16>
__device__ void gram_solve_combine(int b, int n, int idx, float* __restrict__ wsf,
                                   unsigned short* __restrict__ Zf, float* smem)
{
    const int tid = threadIdx.x;
    const int lane = tid & 63, w = tid >> 6;
    float* Xs = wsf + X_OFF;
    float* Fs = wsf + F_OFF;
    float* Z = wsf + Z_OFF;
    const int j4 = tid << 2;

    float fv[MEM][4];
    float g[MEM][4];
    #pragma unroll
    for (int i = 0; i < MEM; ++i) {
        float4 f4 = *(const float4*)&Fs[(b * MEM + i) * DIM + j4];
        float4 xv = *(const float4*)&Xs[(b * MEM + i) * DIM + j4];
        fv[i][0] = f4.x; fv[i][1] = f4.y; fv[i][2] = f4.z; fv[i][3] = f4.w;
        bool act = (i < n);
        g[i][0] = act ? (f4.x - xv.x) : 0.f;
        g[i][1] = act ? (f4.y - xv.y) : 0.f;
        g[i][2] = act ? (f4.z - xv.z) : 0.f;
        g[i][3] = act ? (f4.w - xv.w) : 0.f;
    }
    float gg[15];
    {
        int p = 0;
        #pragma unroll
        for (int i = 0; i < MEM; ++i)
            #pragma unroll
            for (int qq = i; qq < MEM; ++qq) {
                float s = 0.f;
                #pragma unroll
                for (int c = 0; c < 4; ++c) s = fmaf(g[i][c], g[qq][c], s);
                gg[p++] = s;
            }
    }
    #pragma unroll
    for (int off = 1; off < 64; off <<= 1)
        #pragma unroll
        for (int p = 0; p < 15; ++p) gg[p] += __shfl_xor(gg[p], off, 64);
    if (lane == 0) {
        #pragma unroll
        for (int p = 0; p < 15; ++p) smem[p * 16 + w] = gg[p];
    }
    __syncthreads();
    if (tid == 0) {
        float G[MEM][MEM];
        int p = 0;
        for (int i = 0; i < MEM; ++i)
            for (int qq = i; qq < MEM; ++qq) {
                float v = 0.f;
                for (int ww = 0; ww < 16; ++ww) v += smem[p * 16 + ww];
                G[i][qq] = v; G[qq][i] = v; ++p;
            }
        float H[6][6], yv[6];
        for (int i = 0; i < 6; ++i) yv[i] = (i == 0) ? 1.f : 0.f;
        H[0][0] = 0.f;
        for (int i = 0; i < MEM; ++i) {
            float mi = (i < n) ? 1.f : 0.f;
            H[0][1 + i] = mi;
            H[1 + i][0] = mi;
        }
        for (int i = 0; i < MEM; ++i)
            for (int qq = 0; qq < MEM; ++qq) {
                float v;
                if (i < n && qq < n) v = G[i][qq] + ((i == qq) ? LAM_ : 0.f);
                else v = (i == qq) ? 1.f : 0.f;
                H[1 + i][1 + qq] = v;
            }
        for (int col = 0; col < 6; ++col) {
            int piv = col;
            float mv = fabsf(H[col][col]);
            for (int rr = col + 1; rr < 6; ++rr) {
                float av = fabsf(H[rr][col]);
                if (av > mv) { mv = av; piv = rr; }
            }
            if (piv != col) {
                for (int c2 = 0; c2 < 6; ++c2) { float tv = H[col][c2]; H[col][c2] = H[piv][c2]; H[piv][c2] = tv; }
                float tv = yv[col]; yv[col] = yv[piv]; yv[piv] = tv;
            }
            float pv = H[col][col];
            for (int rr = col + 1; rr < 6; ++rr) {
                float f = H[rr][col] / pv;
                H[rr][col] = 0.f;
                for (int c2 = col + 1; c2 < 6; ++c2) H[rr][c2] -= f * H[col][c2];
                yv[rr] -= f * yv[col];
            }
        }
        float sol[6];
        for (int col = 5; col >= 0; --col) {
            float s = yv[col];
            for (int c2 = col + 1; c2 < 6; ++c2) s -= H[col][c2] * sol[c2];
            sol[col] = s / H[col][col];
        }
        for (int i = 0; i < MEM; ++i) smem[240 + i] = sol[1 + i];
    }
    __syncthreads();
    float al[MEM];
    #pragma unroll
    for (int i = 0; i < MEM; ++i) al[i] = smem[240 + i];
    float4 zf = {0.f, 0.f, 0.f, 0.f};
    #pragma unroll
    for (int i = 0; i < MEM; ++i) {
        zf.x = fmaf(al[i], fv[i][0], zf.x);
        zf.y = fmaf(al[i], fv[i][1], zf.y);
        zf.z = fmaf(al[i], fv[i][2], zf.z);
        zf.w = fmaf(al[i], fv[i][3], zf.w);
    }
    *(float4*)&Z[(b << 12) + j4] = zf;
    *(float4*)&Xs[(b * MEM + idx) * DIM + j4] = zf;
    if constexpr (F16) {
        unsigned int* z16 = (unsigned int*)(Zf + ((size_t)b << 12) + j4);
        z16[0] = (unsigned int)f2h(zf.x) | ((unsigned int)f2h(zf.y) << 16);
        z16[1] = (unsigned int)f2h(zf.z) | ((unsigned int)f2h(zf.w) << 16);
    }
}

// ---------------- persistent Anderson solver ----------------
template <bool F16>
__global__ __launch_bounds__(NTHR, 4)
void deq_anderson(const float* __restrict__ x, const float* __restrict__ W,
                  const float* __restrict__ bias, float* __restrict__ out,
                  char* __restrict__ ws)
{
    __shared__ __align__(16) float smem[16384];  // 64 KB
    float* wsf = (float*)ws;
    unsigned int* flags = (unsigned int*)(wsf + BAR_OFF);
    unsigned int* go = flags + 272;              // separate cacheline
    unsigned short* Zf = (unsigned short*)(ws + ZF_BYTE);
    unsigned short* Wf = (unsigned short*)(ws + WF_BYTE);
    const int tid = threadIdx.x;
    const int blk = blockIdx.x;
    const int e = blk * NTHR + tid;
    const int b = e >> 12, j = e & (DIM - 1);
    float* Xs = wsf + X_OFF;
    float* Fs = wsf + F_OFF;
    float* Z = wsf + Z_OFF;
    float* rp = wsf + RP_OFF;
    unsigned int ep = 1;

    // init: X[:,0]=0, X[:,1]=F0, F[:,0]=F0=tanh(x+b), Z=F0
    {
        float f0 = tanhf(x[e] + bias[j]);
        #pragma unroll
        for (int i = 0; i < MEM; ++i) {
            Xs[(b * MEM + i) * DIM + j] = (i == 1) ? f0 : 0.f;
            Fs[(b * MEM + i) * DIM + j] = (i == 0) ? f0 : 0.f;
        }
        Z[e] = f0;
        if constexpr (F16) Zf[e] = f2h(f0);
    }
    if constexpr (F16) {
        convert_w(W, Wf, smem);
        if (blk < GBLK) {
            // PRE=false: Wf from other blocks not yet visible this epoch (r12 bug)
            gemm_tanh_mfma<false>(1, x, bias, Zf, Wf, Z, Fs, rp, smem, flags, go, ep);
        } else {
            gridbar(flags, go, ep);
            if (tid == 0) { rp[blk] = 0.f; rp[NBLK + blk] = 0.f; }
        }
        ++ep;
    } else {
        gridbar(flags, go, ep++);
        gemm_tanh_fp32(1, x, W, bias, wsf, smem);
    }
    gridbar(flags, go, ep++);

    int kend = MAXIT;
    for (int k = 2; k < MAXIT; ++k) {
        float res = phase_res(rp, smem);
        if (k > 2 && res < TOL_) { kend = k; break; }
        const int n = (k < MEM) ? k : MEM;
        const int idx = k % MEM;
        if (blk < BSZ) gram_solve_combine<F16>(blk, n, idx, wsf, Zf, smem);
        if constexpr (F16) {
            if (blk < GBLK)
                gemm_tanh_mfma<true>(idx, x, bias, Zf, Wf, Z, Fs, rp, smem, flags, go, ep);
            else
                gridbar(flags, go, ep);
            ++ep;
        } else {
            gridbar(flags, go, ep++);
            gemm_tanh_fp32(idx, x, W, bias, wsf, smem);
        }
        gridbar(flags, go, ep++);
    }

    const int fidx = (kend - 1) % MEM;
    out[e] = Fs[(b * MEM + fidx) * DIM + j];
}

extern "C" void kernel_launch(void* const* d_in, const int* in_sizes, int n_in,
                              void* d_out, int out_size, void* d_ws, size_t ws_size,
                              hipStream_t stream)
{
    (void)in_sizes; (void)n_in; (void)out_size;
    if (ws_size < (size_t)FP32_WS_FLOATS * sizeof(float)) return;
    const float* x = (const float*)d_in[0];
    const float* W = (const float*)d_in[1];
    const float* b = (const float*)d_in[2];
    float* out = (float*)d_out;
    char* ws = (char*)d_ws;
    // zero flags[256] + go (robust to 0xAA poison; capture-legal)
    hipMemsetAsync(ws + (size_t)BAR_OFF * 4, 0, 1152, stream);
    void* args[] = {(void*)&x, (void*)&W, (void*)&b, (void*)&out, (void*)&ws};
    const void* fn = (ws_size >= WS_NEED)
                         ? reinterpret_cast<const void*>(&deq_anderson<true>)
                         : reinterpret_cast<const void*>(&deq_anderson<false>);
    hipLaunchCooperativeKernel(fn, dim3(NBLK), dim3(NTHR), args, 0, stream);
}

// Round 14
// 240.277 us; speedup vs baseline: 1.1936x; 1.1936x over previous
//
#include <hip/hip_runtime.h>

#define NBLK 256
#define GBLK 128            // active GEMM blocks (BN=32)
#define NTHR 1024
#define BSZ 64
#define DIM 4096
#define MEM 5
#define MAXIT 50
#define TOL_ 0.01f
#define LAM_ 1e-4f

// float-region workspace layout (float offsets)
#define X_OFF 0
#define F_OFF (BSZ * MEM * DIM)
#define Z_OFF (2 * BSZ * MEM * DIM)
#define RP_OFF (Z_OFF + BSZ * DIM)              // residual partials [2][256]
#define BAR_OFF (RP_OFF + 640)                  // flags[256]+go (memset 0 per launch)
#define FP32_WS_FLOATS (RP_OFF + 1024)
// fp16 regions appended (byte offsets)
#define ZF_BYTE ((size_t)(RP_OFF + 1024) * 4)
#define WF_BYTE (ZF_BYTE + (size_t)BSZ * DIM * 2)
#define WS_NEED (WF_BYTE + (size_t)DIM * DIM * 2)

typedef __attribute__((ext_vector_type(8))) _Float16 half8v;  // 8 fp16 (4 VGPRs)
typedef __attribute__((ext_vector_type(4))) float f32x4;

__device__ __forceinline__ unsigned short f2h(float f) {
    _Float16 h = (_Float16)f;           // RNE
    unsigned short u;
    __builtin_memcpy(&u, &h, 2);
    return u;
}

// ---- zero-contention grid barrier (round-6/8 proven; best of 5 variants) ----
// Leg 1: leaders store own flag (parallel, no RMW); block 0 polls all 256
// with 256 threads. Leg 2: block 0 publishes single `go`; 255 single threads
// poll it. One release-wb + one acquire-inv per block per barrier. r13
// lesson: do NOT issue loads just before the release fence (vmcnt drain
// serializes them into barrier arrival).
__device__ __forceinline__ void gridbar(unsigned int* flags, unsigned int* go,
                                        unsigned int e)
{
    __syncthreads();
    const int tid = threadIdx.x;
    if (blockIdx.x == 0) {
        if (tid == 0) {
            __builtin_amdgcn_fence(__ATOMIC_RELEASE, "agent");
            __hip_atomic_store(&flags[0], e, __ATOMIC_RELAXED,
                               __HIP_MEMORY_SCOPE_AGENT);
        }
        if (tid < NBLK) {
            while (__hip_atomic_load(&flags[tid], __ATOMIC_RELAXED,
                                     __HIP_MEMORY_SCOPE_AGENT) < e)
                __builtin_amdgcn_s_sleep(1);
        }
        __syncthreads();
        if (tid == 0) {
            __builtin_amdgcn_fence(__ATOMIC_ACQUIRE, "agent");
            __hip_atomic_store(go, e, __ATOMIC_RELAXED,
                               __HIP_MEMORY_SCOPE_AGENT);
        }
    } else {
        if (tid == 0) {
            __builtin_amdgcn_fence(__ATOMIC_RELEASE, "agent");
            __hip_atomic_store(&flags[blockIdx.x], e, __ATOMIC_RELAXED,
                               __HIP_MEMORY_SCOPE_AGENT);
            while (__hip_atomic_load(go, __ATOMIC_RELAXED,
                                     __HIP_MEMORY_SCOPE_AGENT) < e)
                __builtin_amdgcn_s_sleep(1);
            __builtin_amdgcn_fence(__ATOMIC_ACQUIRE, "agent");
        }
    }
    __syncthreads();
}

// ---------------- one-time W -> packed fp16 conversion ----------------
// Layout per 16-col group ng: Wf[ng*65536 + ks*512 + lane*8 + e],
// k = ks*32 + (lane>>4)*8 + e, j = ng*16 + (lane&15).
__device__ void convert_w(const float* __restrict__ W, unsigned short* __restrict__ Wf,
                          float* smem)
{
    const int tid = threadIdx.x;
    const int blk = blockIdx.x;
    const int jc = blk << 4;
    for (int sc = 0; sc < 8; ++sc) {
        __syncthreads();
        #pragma unroll
        for (int h = 0; h < 2; ++h) {
            int rrow = (tid >> 2) + (h << 8);
            int seg = tid & 3;
            float4 v = *(const float4*)&W[(size_t)((sc << 9) + rrow) * DIM + jc + (seg << 2)];
            float* dst = smem + rrow * 17 + (seg << 2);
            dst[0] = v.x; dst[1] = v.y; dst[2] = v.z; dst[3] = v.w;
        }
        __syncthreads();
        unsigned int* of = (unsigned int*)(Wf + ((size_t)blk * 128 + sc * 16) * 512);
        #pragma unroll
        for (int it = 0; it < 4; ++it) {
            int o = tid + (it << 10);
            int ksl = o >> 8, ln = (o >> 2) & 63, ep = o & 3;
            int kl = (ksl << 5) + ((ln >> 4) << 3) + (ep << 1);
            float w0 = smem[kl * 17 + (ln & 15)];
            float w1 = smem[(kl + 1) * 17 + (ln & 15)];
            of[o] = (unsigned int)f2h(w0) | ((unsigned int)f2h(w1) << 16);
        }
    }
    __syncthreads();
}

// ---------------- fp16 MFMA GEMM + tanh + residual partials (BN=32) ----------
// 128 active blocks x 32 cols; 16 waves K-split 16-way; single-term fp16
// (fp16 11-bit mantissa: pre-tanh error ~1e-4, below trajectory noise).
__device__ __forceinline__ void gemm_tanh_mfma(
    int idx, const float* __restrict__ x, const float* __restrict__ bias,
    const unsigned short* __restrict__ Zf, const unsigned short* __restrict__ Wf,
    float* __restrict__ Z, float* __restrict__ Fs, float* __restrict__ rp, float* smem)
{
    const int tid = threadIdx.x;
    const int cb = blockIdx.x;              // 0..127
    const int lane = tid & 63;
    const int w = tid >> 6;                 // wave 0..15
    const int r0 = lane & 15;
    const int kg = lane >> 4;
    f32x4 acc[4][2] = {};

    const unsigned short* b0 = Wf + (size_t)(cb * 2) * 65536;
    const unsigned short* b1 = Wf + (size_t)(cb * 2 + 1) * 65536;
    const int ksbase = w << 3;

    #pragma unroll 2
    for (int s = 0; s < 8; ++s) {
        const int ks = ksbase + s;
        const size_t bo = ((size_t)ks << 9) + (lane << 3);
        half8v B0 = *(const half8v*)(b0 + bo);
        half8v B1 = *(const half8v*)(b1 + bo);
        const int kbase = (ks << 5) + (kg << 3);
        #pragma unroll
        for (int m = 0; m < 4; ++m) {
            const size_t ao = (size_t)((m << 4) + r0) * DIM + kbase;
            half8v Ah = *(const half8v*)(Zf + ao);
            acc[m][0] = __builtin_amdgcn_mfma_f32_16x16x32_f16(Ah, B0, acc[m][0], 0, 0, 0);
            acc[m][1] = __builtin_amdgcn_mfma_f32_16x16x32_f16(Ah, B1, acc[m][1], 0, 0, 0);
        }
    }
    // cross-wave reduce: 4 rounds of 4 sections; section = 2048 floats + pad 4
    const int row = tid >> 4, cc = tid & 15;
    const int m_o = row >> 4, rl = row & 15;
    const int lsrc = cc + ((rl >> 2) << 4), reg = rl & 3;
    float sum0 = 0.f, sum1 = 0.f;
    #pragma unroll
    for (int rnd = 0; rnd < 4; ++rnd) {
        __syncthreads();
        if ((w >> 2) == rnd) {
            float* sec = smem + (w & 3) * 2052;
            #pragma unroll
            for (int m = 0; m < 4; ++m) {
                *(f32x4*)(sec + ((m * 2 + 0) << 8) + (lane << 2)) = acc[m][0];
                *(f32x4*)(sec + ((m * 2 + 1) << 8) + (lane << 2)) = acc[m][1];
            }
        }
        __syncthreads();
        #pragma unroll
        for (int p = 0; p < 4; ++p) {
            sum0 += smem[p * 2052 + ((m_o * 2 + 0) << 8) + (lsrc << 2) + reg];
            sum1 += smem[p * 2052 + ((m_o * 2 + 1) << 8) + (lsrc << 2) + reg];
        }
    }
    // epilogue: tanh, F-slot write, residual partials (2 cols/thread)
    const int j0 = (cb << 5) + cc;
    const int j1 = j0 + 16;
    float fz0 = tanhf(sum0 + x[(row << 12) + j0] + bias[j0]);
    float fz1 = tanhf(sum1 + x[(row << 12) + j1] + bias[j1]);
    Fs[(row * MEM + idx) * DIM + j0] = fz0;
    Fs[(row * MEM + idx) * DIM + j1] = fz1;
    float d0 = fz0 - Z[(row << 12) + j0];
    float d1 = fz1 - Z[(row << 12) + j1];
    float lnum = d0 * d0 + d1 * d1;
    float lden = fz0 * fz0 + fz1 * fz1;
    #pragma unroll
    for (int off = 1; off < 64; off <<= 1) {
        lnum += __shfl_xor(lnum, off, 64);
        lden += __shfl_xor(lden, off, 64);
    }
    if (lane == 0) { smem[8448 + w] = lnum; smem[8480 + w] = lden; }
    __syncthreads();
    if (tid == 0) {
        float a = 0.f, b2 = 0.f;
        #pragma unroll
        for (int i = 0; i < 16; ++i) { a += smem[8448 + i]; b2 += smem[8480 + i]; }
        rp[cb] = a;
        rp[NBLK + cb] = b2;
    }
}

// ---------------- fp32 fallback GEMM (round-2, proven; 256 blocks) ----------
__device__ __forceinline__ void gemm_tanh_fp32(
    int idx, const float* __restrict__ x, const float* __restrict__ W,
    const float* __restrict__ bias, float* __restrict__ wsf, float* smem)
{
    const int tid = threadIdx.x;
    const int blk = blockIdx.x;
    const int lane = tid & 63;
    const int w = tid >> 6;
    const int r = w >> 2;
    const int q = w & 3;
    const int jcq = (blk << 4) + (q << 2);
    float* Z = wsf + Z_OFF;
    float* Fs = wsf + F_OFF;
    float* rp = wsf + RP_OFF;

    float acc0 = 0.f, acc1 = 0.f, acc2 = 0.f, acc3 = 0.f;
    const int lx = lane & 15;
    const float* inrow = smem + (r << 12) + (lane << 6);
    const int srow = tid >> 4;
    const int sg = tid & 15;

    for (int step = 0; step < 16; ++step) {
        #pragma unroll
        for (int i = 0; i < 4; ++i) {
            float4 v = *(const float4*)&Z[srow * DIM + (i << 10) + (step << 6) + (sg << 2)];
            *(float4*)&smem[(i << 12) + (srow << 6) + ((sg ^ (srow & 15)) << 2)] = v;
        }
        __syncthreads();
        const float* wbase = W + (size_t)((r << 10) + (step << 6)) * DIM + jcq;
        #pragma unroll 2
        for (int s = 0; s < 16; ++s) {
            float4 in4 = *(const float4*)&inrow[(s ^ lx) << 2];
            const float* wr = wbase + (size_t)(s << 2) * DIM;
            #pragma unroll
            for (int t = 0; t < 4; ++t) {
                float iv = (t == 0) ? in4.x : (t == 1) ? in4.y : (t == 2) ? in4.z : in4.w;
                float4 wq = *(const float4*)(wr + (size_t)t * DIM);
                acc0 = fmaf(iv, wq.x, acc0);
                acc1 = fmaf(iv, wq.y, acc1);
                acc2 = fmaf(iv, wq.z, acc2);
                acc3 = fmaf(iv, wq.w, acc3);
            }
        }
        __syncthreads();
    }
    {
        float* rrow = smem + r * 1088 + lane * 17 + (q << 2);
        rrow[0] = acc0; rrow[1] = acc1; rrow[2] = acc2; rrow[3] = acc3;
    }
    __syncthreads();
    const int row = tid >> 4, cc = tid & 15;
    const int boff = row * 17 + cc;
    float sum = smem[boff] + smem[1088 + boff] + smem[2176 + boff] + smem[3264 + boff];
    const int j = (blk << 4) + cc;
    float fz = tanhf(sum + x[(row << 12) + j] + bias[j]);
    Fs[(row * MEM + idx) * DIM + j] = fz;
    float d = fz - Z[(row << 12) + j];
    float lnum = d * d, lden = fz * fz;
    #pragma unroll
    for (int off = 1; off < 64; off <<= 1) {
        lnum += __shfl_xor(lnum, off, 64);
        lden += __shfl_xor(lden, off, 64);
    }
    if (lane == 0) { smem[8448 + w] = lnum; smem[8480 + w] = lden; }
    __syncthreads();
    if (tid == 0) {
        float a = 0.f, b2 = 0.f;
        for (int i = 0; i < 16; ++i) { a += smem[8448 + i]; b2 += smem[8480 + i]; }
        rp[blk] = a;
        rp[NBLK + blk] = b2;
    }
}

// ---------------- residual reduce (every block, deterministic) -----------
__device__ __forceinline__ float phase_res(const float* __restrict__ rp, float* smem)
{
    const int tid = threadIdx.x;
    const int lane = tid & 63, w = tid >> 6;
    float a = (tid < NBLK) ? rp[tid] : 0.f;
    float b = (tid < NBLK) ? rp[NBLK + tid] : 0.f;
    #pragma unroll
    for (int off = 1; off < 64; off <<= 1) {
        a += __shfl_xor(a, off, 64);
        b += __shfl_xor(b, off, 64);
    }
    if (lane == 0) { smem[w] = a; smem[16 + w] = b; }
    __syncthreads();
    if (tid == 0) {
        float sa = 0.f, sb = 0.f;
        for (int i = 0; i < 16; ++i) { sa += smem[i]; sb += smem[16 + i]; }
        smem[32] = sqrtf(sa) / (1e-5f + sqrtf(sb));
    }
    __syncthreads();
    float res = smem[32];
    __syncthreads();
    return res;
}

// ---- per-batch-row: Gram + 6x6 bordered solve + alpha-combine ----
template <bool F16>
__device__ void gram_solve_combine(int b, int n, int idx, float* __restrict__ wsf,
                                   unsigned short* __restrict__ Zf, float* smem)
{
    const int tid = threadIdx.x;
    const int lane = tid & 63, w = tid >> 6;
    float* Xs = wsf + X_OFF;
    float* Fs = wsf + F_OFF;
    float* Z = wsf + Z_OFF;
    const int j4 = tid << 2;

    float g[MEM][4];
    #pragma unroll
    for (int i = 0; i < MEM; ++i) {
        float4 fv = *(const float4*)&Fs[(b * MEM + i) * DIM + j4];
        float4 xv = *(const float4*)&Xs[(b * MEM + i) * DIM + j4];
        bool act = (i < n);
        g[i][0] = act ? (fv.x - xv.x) : 0.f;
        g[i][1] = act ? (fv.y - xv.y) : 0.f;
        g[i][2] = act ? (fv.z - xv.z) : 0.f;
        g[i][3] = act ? (fv.w - xv.w) : 0.f;
    }
    float gg[15];
    {
        int p = 0;
        #pragma unroll
        for (int i = 0; i < MEM; ++i)
            #pragma unroll
            for (int qq = i; qq < MEM; ++qq) {
                float s = 0.f;
                #pragma unroll
                for (int c = 0; c < 4; ++c) s = fmaf(g[i][c], g[qq][c], s);
                gg[p++] = s;
            }
    }
    #pragma unroll
    for (int off = 1; off < 64; off <<= 1)
        #pragma unroll
        for (int p = 0; p < 15; ++p) gg[p] += __shfl_xor(gg[p], off, 64);
    if (lane == 0) {
        #pragma unroll
        for (int p = 0; p < 15; ++p) smem[p * 16 + w] = gg[p];
    }
    __syncthreads();
    if (tid == 0) {
        float G[MEM][MEM];
        int p = 0;
        for (int i = 0; i < MEM; ++i)
            for (int qq = i; qq < MEM; ++qq) {
                float v = 0.f;
                for (int ww = 0; ww < 16; ++ww) v += smem[p * 16 + ww];
                G[i][qq] = v; G[qq][i] = v; ++p;
            }
        float H[6][6], yv[6];
        for (int i = 0; i < 6; ++i) yv[i] = (i == 0) ? 1.f : 0.f;
        H[0][0] = 0.f;
        for (int i = 0; i < MEM; ++i) {
            float mi = (i < n) ? 1.f : 0.f;
            H[0][1 + i] = mi;
            H[1 + i][0] = mi;
        }
        for (int i = 0; i < MEM; ++i)
            for (int qq = 0; qq < MEM; ++qq) {
                float v;
                if (i < n && qq < n) v = G[i][qq] + ((i == qq) ? LAM_ : 0.f);
                else v = (i == qq) ? 1.f : 0.f;
                H[1 + i][1 + qq] = v;
            }
        for (int col = 0; col < 6; ++col) {
            int piv = col;
            float mv = fabsf(H[col][col]);
            for (int rr = col + 1; rr < 6; ++rr) {
                float av = fabsf(H[rr][col]);
                if (av > mv) { mv = av; piv = rr; }
            }
            if (piv != col) {
                for (int c2 = 0; c2 < 6; ++c2) { float tv = H[col][c2]; H[col][c2] = H[piv][c2]; H[piv][c2] = tv; }
                float tv = yv[col]; yv[col] = yv[piv]; yv[piv] = tv;
            }
            float pv = H[col][col];
            for (int rr = col + 1; rr < 6; ++rr) {
                float f = H[rr][col] / pv;
                H[rr][col] = 0.f;
                for (int c2 = col + 1; c2 < 6; ++c2) H[rr][c2] -= f * H[col][c2];
                yv[rr] -= f * yv[col];
            }
        }
        float sol[6];
        for (int col = 5; col >= 0; --col) {
            float s = yv[col];
            for (int c2 = col + 1; c2 < 6; ++c2) s -= H[col][c2] * sol[c2];
            sol[col] = s / H[col][col];
        }
        for (int i = 0; i < MEM; ++i) smem[240 + i] = sol[1 + i];
    }
    __syncthreads();
    float al[MEM];
    #pragma unroll
    for (int i = 0; i < MEM; ++i) al[i] = smem[240 + i];
    float4 zf = {0.f, 0.f, 0.f, 0.f};
    #pragma unroll
    for (int i = 0; i < MEM; ++i) {
        float4 fv = *(const float4*)&Fs[(b * MEM + i) * DIM + j4];
        zf.x = fmaf(al[i], fv.x, zf.x);
        zf.y = fmaf(al[i], fv.y, zf.y);
        zf.z = fmaf(al[i], fv.z, zf.z);
        zf.w = fmaf(al[i], fv.w, zf.w);
    }
    *(float4*)&Z[(b << 12) + j4] = zf;
    *(float4*)&Xs[(b * MEM + idx) * DIM + j4] = zf;
    if constexpr (F16) {
        unsigned int* z16 = (unsigned int*)(Zf + ((size_t)b << 12) + j4);
        z16[0] = (unsigned int)f2h(zf.x) | ((unsigned int)f2h(zf.y) << 16);
        z16[1] = (unsigned int)f2h(zf.z) | ((unsigned int)f2h(zf.w) << 16);
    }
}

// ---------------- persistent Anderson solver ----------------
template <bool F16>
__global__ __launch_bounds__(NTHR, 4)
void deq_anderson(const float* __restrict__ x, const float* __restrict__ W,
                  const float* __restrict__ bias, float* __restrict__ out,
                  char* __restrict__ ws)
{
    __shared__ __align__(16) float smem[16384];  // 64 KB
    float* wsf = (float*)ws;
    unsigned int* flags = (unsigned int*)(wsf + BAR_OFF);
    unsigned int* go = flags + 272;              // separate cacheline
    unsigned short* Zf = (unsigned short*)(ws + ZF_BYTE);
    unsigned short* Wf = (unsigned short*)(ws + WF_BYTE);
    const int tid = threadIdx.x;
    const int blk = blockIdx.x;
    const int e = blk * NTHR + tid;
    const int b = e >> 12, j = e & (DIM - 1);
    float* Xs = wsf + X_OFF;
    float* Fs = wsf + F_OFF;
    float* Z = wsf + Z_OFF;
    float* rp = wsf + RP_OFF;
    unsigned int ep = 1;

    // init: X[:,0]=0, X[:,1]=F0, F[:,0]=F0=tanh(x+b), Z=F0
    {
        float f0 = tanhf(x[e] + bias[j]);
        #pragma unroll
        for (int i = 0; i < MEM; ++i) {
            Xs[(b * MEM + i) * DIM + j] = (i == 1) ? f0 : 0.f;
            Fs[(b * MEM + i) * DIM + j] = (i == 0) ? f0 : 0.f;
        }
        Z[e] = f0;
        if constexpr (F16) Zf[e] = f2h(f0);
    }
    if constexpr (F16) convert_w(W, Wf, smem);
    gridbar(flags, go, ep++);
    if constexpr (F16) {
        if (blk < GBLK)
            gemm_tanh_mfma(1, x, bias, Zf, Wf, Z, Fs, rp, smem);
        else if (tid == 0) { rp[blk] = 0.f; rp[NBLK + blk] = 0.f; }
    } else {
        gemm_tanh_fp32(1, x, W, bias, wsf, smem);
    }
    gridbar(flags, go, ep++);

    int kend = MAXIT;
    for (int k = 2; k < MAXIT; ++k) {
        float res = phase_res(rp, smem);
        if (k > 2 && res < TOL_) { kend = k; break; }
        const int n = (k < MEM) ? k : MEM;
        const int idx = k % MEM;
        if (blk < BSZ) gram_solve_combine<F16>(blk, n, idx, wsf, Zf, smem);
        gridbar(flags, go, ep++);
        if constexpr (F16) {
            if (blk < GBLK)
                gemm_tanh_mfma(idx, x, bias, Zf, Wf, Z, Fs, rp, smem);
        } else {
            gemm_tanh_fp32(idx, x, W, bias, wsf, smem);
        }
        gridbar(flags, go, ep++);
    }

    const int fidx = (kend - 1) % MEM;
    out[e] = Fs[(b * MEM + fidx) * DIM + j];
}

extern "C" void kernel_launch(void* const* d_in, const int* in_sizes, int n_in,
                              void* d_out, int out_size, void* d_ws, size_t ws_size,
                              hipStream_t stream)
{
    (void)in_sizes; (void)n_in; (void)out_size;
    if (ws_size < (size_t)FP32_WS_FLOATS * sizeof(float)) return;
    const float* x = (const float*)d_in[0];
    const float* W = (const float*)d_in[1];
    const float* b = (const float*)d_in[2];
    float* out = (float*)d_out;
    char* ws = (char*)d_ws;
    // zero flags[256] + go (robust to 0xAA poison; capture-legal)
    hipMemsetAsync(ws + (size_t)BAR_OFF * 4, 0, 1152, stream);
    void* args[] = {(void*)&x, (void*)&W, (void*)&b, (void*)&out, (void*)&ws};
    const void* fn = (ws_size >= WS_NEED)
                         ? reinterpret_cast<const void*>(&deq_anderson<true>)
                         : reinterpret_cast<const void*>(&deq_anderson<false>);
    hipLaunchCooperativeKernel(fn, dim3(NBLK), dim3(NTHR), args, 0, stream);
}